// Round 8
// baseline (167.052 us; speedup 1.0000x reference)
//
#include <hip/hip_runtime.h>

typedef unsigned short u16;
typedef unsigned int   u32;
typedef __attribute__((ext_vector_type(8))) short bf16x8;
typedef __attribute__((ext_vector_type(4))) float f32x4;
typedef __attribute__((ext_vector_type(2))) unsigned int u32x2;

__device__ __forceinline__ float bf2f(u16 u) { return __uint_as_float(((u32)u) << 16); }
// round-half-up (ties away): identical to RNE except exact ties; 2 VALU ops.
__device__ __forceinline__ u16 f2bf(float f) {
    return (u16)((__float_as_uint(f) + 0x8000u) >> 16);
}
// packed RNE f32->bf16 pair: one VALU op for two conversions
__device__ __forceinline__ u32 cvt_pk_bf16(float lo, float hi) {
    u32 r;
    asm("v_cvt_pk_bf16_f32 %0, %1, %2" : "=v"(r) : "v"(lo), "v"(hi));
    return r;
}
__device__ __forceinline__ void gload16(const void* g, void* l) {
    __builtin_amdgcn_global_load_lds((const __attribute__((address_space(1))) void*)g,
                                     (__attribute__((address_space(3))) void*)l, 16, 0, 0);
}
#define VMCNT(n) asm volatile("s_waitcnt vmcnt(" #n ")" ::: "memory")

// ---------------------------------------------------------------------------
// Fused fp32->bf16 conversion for hs + Wq + Wk + Wv (contiguous dsts in ws).
// ---------------------------------------------------------------------------
struct us4 { u16 x, y, z, w; };
__global__ void cvt_all(const float* __restrict__ hs, const float* __restrict__ wq,
                        const float* __restrict__ wk, const float* __restrict__ wv,
                        u16* __restrict__ dst)
{
    int i = blockIdx.x * blockDim.x + threadIdx.x;
    const int stride = gridDim.x * blockDim.x;
    us4* d4 = (us4*)dst;
    for (; i < 1835008; i += stride) {
        const float4* s4;
        int j = i;
        if (j < 1048576)      { s4 = (const float4*)hs; }
        else if (j < 1310720) { s4 = (const float4*)wq; j -= 1048576; }
        else if (j < 1572864) { s4 = (const float4*)wk; j -= 1310720; }
        else                  { s4 = (const float4*)wv; j -= 1572864; }
        float4 v = s4[j];
        us4 o;
        o.x = f2bf(v.x); o.y = f2bf(v.y); o.z = f2bf(v.z); o.w = f2bf(v.w);
        d4[i] = o;
    }
}

// ---------------------------------------------------------------------------
// Kernel 1: fused QKV projection — unchanged from R7 (128x128 tile, BK=64,
// double-buffered counted-vmcnt pipeline, VMCNT(8)+s_barrier, peeled tail,
// setprio; grid (24,32), blockIdx.x = mat*8+cb fastest for XCD-resident W).
// ---------------------------------------------------------------------------
__global__ __launch_bounds__(256) void qkv_gemm(
    const u16* __restrict__ hs,
    const u16* __restrict__ Wq, const u16* __restrict__ Wk, const u16* __restrict__ Wv,
    const float* __restrict__ bq, const float* __restrict__ bk, const float* __restrict__ bv,
    u16* __restrict__ oq, u16* __restrict__ ok, u16* __restrict__ ovt)
{
    __shared__ u16 smem[32768];        // sA0 sB0 sA1 sB1, 8192 u16 each
    u16* sA0 = smem;                   // epilogue: 4 waves x 64x72 strips [0,18432)
    u16* sB0 = smem + 8192;
    u16* sA1 = smem + 16384;
    u16* sB1 = smem + 24576;

    const int tid  = threadIdx.x;
    const int lane = tid & 63;
    const int w    = tid >> 6;
    const int c15  = lane & 15;
    const int q4   = lane >> 4;
    const int mat  = blockIdx.x >> 3;   // 0=q 1=k 2=v
    const int cb   = blockIdx.x & 7;    // col block (128 cols = 2 heads)
    const int rb   = blockIdx.y;        // row block (128 rows)
    const int wr   = w >> 1, wc = w & 1;

    const u16*   W    = (mat == 0) ? Wq : (mat == 1 ? Wk : Wv);
    const float* bias = (mat == 0) ? bq : (mat == 1 ? bk : bv);

    f32x4 acc[4][4] = {};

    const int rs = tid >> 3;
    const int cs = ((tid & 7) ^ (rs & 7)) * 8;
    const u16* gA = hs + (rb * 128) * 1024;
    const u16* gB = W + (cb * 128) * 1024;

    auto stageQ = [&](u16* dA, u16* dB, int kb) {
#pragma unroll
        for (int p = 0; p < 4; ++p)
            gload16(gA + (rs + 32 * p) * 1024 + kb + cs, dA + p * 2048 + w * 512);
#pragma unroll
        for (int p = 0; p < 4; ++p)
            gload16(gB + (rs + 32 * p) * 1024 + kb + cs, dB + p * 2048 + w * 512);
    };

    auto computeQ = [&](const u16* sA, const u16* sB) {
        __builtin_amdgcn_s_setprio(1);
#pragma unroll
        for (int kk = 0; kk < 2; ++kk) {
            const int cpos = ((kk * 4 + q4) ^ (c15 & 7)) * 8;
            bf16x8 af[4], bf[4];
#pragma unroll
            for (int mt = 0; mt < 4; ++mt)
                af[mt] = *(const bf16x8*)(sA + (wr * 64 + mt * 16 + c15) * 64 + cpos);
#pragma unroll
            for (int nt = 0; nt < 4; ++nt)
                bf[nt] = *(const bf16x8*)(sB + (wc * 64 + nt * 16 + c15) * 64 + cpos);
#pragma unroll
            for (int mt = 0; mt < 4; ++mt)
#pragma unroll
                for (int nt = 0; nt < 4; ++nt)
                    acc[mt][nt] = __builtin_amdgcn_mfma_f32_16x16x32_bf16(
                        af[mt], bf[nt], acc[mt][nt], 0, 0, 0);
        }
        __builtin_amdgcn_s_setprio(0);
    };

    // ---- prologue: K-steps 0,1 in flight ----
    stageQ(sA0, sB0, 0);
    stageQ(sA1, sB1, 64);

#pragma unroll 1
    for (int T = 0; T < 14; T += 2) {
        VMCNT(8);
        __builtin_amdgcn_s_barrier();
        __builtin_amdgcn_sched_barrier(0);
        computeQ(sA0, sB0);
        __builtin_amdgcn_s_barrier();
        __builtin_amdgcn_sched_barrier(0);
        stageQ(sA0, sB0, (T + 2) * 64);

        VMCNT(8);
        __builtin_amdgcn_s_barrier();
        __builtin_amdgcn_sched_barrier(0);
        computeQ(sA1, sB1);
        __builtin_amdgcn_s_barrier();
        __builtin_amdgcn_sched_barrier(0);
        stageQ(sA1, sB1, (T + 3) * 64);
    }
    VMCNT(8);
    __builtin_amdgcn_s_barrier();
    __builtin_amdgcn_sched_barrier(0);
    computeQ(sA0, sB0);
    VMCNT(0);
    __builtin_amdgcn_s_barrier();
    __builtin_amdgcn_sched_barrier(0);
    computeQ(sA1, sB1);

    // ---- epilogue: bias add, per-wave LDS transpose, coalesced 16B stores ----
    __syncthreads();
    const int h = cb * 2 + wc;
    float bvv[4];
#pragma unroll
    for (int nt = 0; nt < 4; ++nt)
        bvv[nt] = bias[cb * 128 + wc * 64 + nt * 16 + c15];

    u16* sc = smem + w * 4608;          // 64 rows x 72 cols per wave
    if (mat != 2) {
        u16* dst = (mat == 0) ? oq : ok;
#pragma unroll
        for (int mt = 0; mt < 4; ++mt)
#pragma unroll
            for (int nt = 0; nt < 4; ++nt)
#pragma unroll
                for (int rr = 0; rr < 4; ++rr)
                    sc[(mt * 16 + q4 * 4 + rr) * 72 + nt * 16 + c15] =
                        f2bf(acc[mt][nt][rr] + bvv[nt]);
#pragma unroll
        for (int p = 0; p < 8; ++p) {
            const int s = p * 64 + lane;
            const int rl = s >> 3, oct = (s & 7) * 8;
            bf16x8 vv = *(const bf16x8*)(sc + rl * 72 + oct);
            const int n = rb * 128 + wr * 64 + rl;
            const int bb = n >> 11, nn = n & 2047;
            *(bf16x8*)(dst + (((bb * 16 + h) * 2048) + nn) * 64 + oct) = vv;
        }
    } else {
#pragma unroll
        for (int mt = 0; mt < 4; ++mt)
#pragma unroll
            for (int nt = 0; nt < 4; ++nt)
#pragma unroll
                for (int rr = 0; rr < 4; ++rr)
                    sc[(nt * 16 + c15) * 72 + mt * 16 + q4 * 4 + rr] =
                        f2bf(acc[mt][nt][rr] + bvv[nt]);
#pragma unroll
        for (int p = 0; p < 8; ++p) {
            const int s = p * 64 + lane;
            const int dr = s >> 3, noct = (s & 7) * 8;
            bf16x8 vv = *(const bf16x8*)(sc + dr * 72 + noct);
            const int n0 = rb * 128 + wr * 64 + noct;
            const int bb = n0 >> 11, nn = n0 & 2047;
            *(bf16x8*)(ovt + ((bb * 16 + h) * 64 + dr) * 2048 + nn) = vv;
        }
    }
}

// ---------------------------------------------------------------------------
// Kernel 2: flash attention — R8: TLP unlock.  R4-R7 counters: no pipe >36%,
// OccupancyPercent 16-20% (grid 512 blocks = exactly 2 blocks/CU, 2 waves/
// SIMD) -> latency-bound serial QK^T->softmax->PV chain.  LDS (32 KB) and
// VGPR both allow 4 blocks/CU; only the grid forbids it.
//   * q-tile 64 rows (was 128): grid (32 bh, 32 qt) = 1024 blocks = 4/CU,
//     16 waves/CU.  4 waves x 16 q-rows (rt dim removed).
//   * KVBLK=64 double-buffered: 4 x 8 KB = 32 KB LDS.  Same R4 pipeline:
//     distance-2 prefetch, VMCNT(4)+raw s_barrier, peeled last 2 tiles.
//   * Same R2-proven tile math: perm-key K staging (XOR-swizzled), V^T
//     [d][key] stride 64 (XOR-swizzled by d&7), in-register softmax with
//     the virtual-key-order full-K32 PV.
//   * l_acc tree-sum (8-deep chain instead of 32).
//   * __launch_bounds__(256,4) caps VGPR at 128 for 4 blocks/CU.
// Cost: per-wave LDS reads unchanged, 2x waves -> ~2.1 GB LDS reads (~40 us
// aggregate demand) = the predicted new ceiling.
// ---------------------------------------------------------------------------
__global__ __launch_bounds__(256, 4) void attn(
    const u16* __restrict__ qm, const u16* __restrict__ km, const u16* __restrict__ vtm,
    const float* __restrict__ mask, float* __restrict__ out)
{
    __shared__ u16 sK0[4096];          // K tile: 64 perm-key rows x 64 d
    __shared__ u16 sV0[4096];          // V^T tile: 64 d rows x 64 keys
    __shared__ u16 sK1[4096];
    __shared__ u16 sV1[4096];

    const int tid = threadIdx.x, lane = tid & 63, w = tid >> 6;
    const int c15 = lane & 15, q4 = lane >> 4;
    const int bh = blockIdx.x;         // 0..31 FASTEST -> XCD locality
    const int qt = blockIdx.y;         // q tile 0..31 (64 rows each)
    const int b = bh >> 4;

    // Q fragments (B operand of S^T = K.Q^T): rows qt*64 + w*16 + c15
    bf16x8 qf[2];
    const u16* qbase = qm + (bh * 2048 + qt * 64 + w * 16) * 64;
#pragma unroll
    for (int kt = 0; kt < 2; ++kt)
        qf[kt] = *(const bf16x8*)(qbase + c15 * 64 + kt * 32 + q4 * 8);

    float l_acc = 0.f;
    f32x4 accO[4] = {};

    const u16* kbase  = km  + bh * 2048 * 64;
    const u16* vtbase = vtm + bh * 64 * 2048;   // [d][n]

    // staging: each 64x64 tile = 512 16B chunks, 2/thread (chunk c=p*256+tid)
    //   row = 32p + (tid>>3); LDS offset = p*2048 + tid*8 (linear, dest =
    //   wave-uniform base + lane*16B); src col XOR-swizzled by row&7.
    const int rs   = tid >> 3;                  // 0..31
    const int cls  = ((tid & 7) ^ (rs & 7)) * 8;
    const int prK  = (rs & 3) | ((rs & 0x0C) << 1) | ((rs & 0x10) >> 2);  // perm key
    const int ldsW = w * 512;                   // wave-uniform LDS dest offset

    const float* mbase = mask + b * 2048 + 8 * q4;

    auto stage = [&](u16* dK, u16* dV, int TT) {
        const u16* kg = kbase + TT * 64 * 64;
        const u16* vg = vtbase + TT * 64;
#pragma unroll
        for (int p = 0; p < 2; ++p)
            gload16(kg + (prK + 32 * p) * 64 + cls, dK + p * 2048 + ldsW);
#pragma unroll
        for (int p = 0; p < 2; ++p)
            gload16(vg + (rs + 32 * p) * 2048 + cls, dV + p * 2048 + ldsW);
    };

    // ---- compute one 64-key tile ----
    auto compute64 = [&](const u16* sKh, const u16* sVT, int kb) {
        // mask per key, pre-scaled by log2e.  (t,rr) <-> real key
        // kb + 32*(t>>1) + 8*q4 + 4*(t&1) + rr  (aligned float4 per t).
        float mkv[4][4];
#pragma unroll
        for (int t = 0; t < 4; ++t) {
            float4 m4 = *(const float4*)(mbase + kb + 32 * (t >> 1) + 4 * (t & 1));
            mkv[t][0] = m4.x * 1.4426950408889634f;
            mkv[t][1] = m4.y * 1.4426950408889634f;
            mkv[t][2] = m4.z * 1.4426950408889634f;
            mkv[t][3] = m4.w * 1.4426950408889634f;
        }

        // --- S^T = K Q^T: lane(q4,c15) reg rr = S[rho=t*16+q4*4+rr][c15]
        f32x4 accST[4] = {};
        __builtin_amdgcn_s_setprio(1);
#pragma unroll
        for (int kt = 0; kt < 2; ++kt) {
            bf16x8 kf[4];
#pragma unroll
            for (int t = 0; t < 4; ++t) {
                const int rho = t * 16 + c15;
                const int cpos = (kt * 4 + q4) ^ (rho & 7);
                kf[t] = *(const bf16x8*)(sKh + rho * 64 + cpos * 8);
            }
#pragma unroll
            for (int t = 0; t < 4; ++t)
                accST[t] = __builtin_amdgcn_mfma_f32_16x16x32_bf16(
                    kf[t], qf[kt], accST[t], 0, 0, 0);
        }
        __builtin_amdgcn_s_setprio(0);

        // --- softmax in-register: p = exp2(s*0.125*log2e + m*log2e)
        u32 pu[4][2];
#pragma unroll
        for (int t = 0; t < 4; ++t) {
            float p[4];
#pragma unroll
            for (int rr = 0; rr < 4; ++rr)
                p[rr] = __builtin_amdgcn_exp2f(
                    fmaf(accST[t][rr], 0.18033688011112042f, mkv[t][rr]));
            l_acc += (p[0] + p[1]) + (p[2] + p[3]);
            pu[t][0] = cvt_pk_bf16(p[0], p[1]);
            pu[t][1] = cvt_pk_bf16(p[2], p[3]);
        }

        // --- PV full-K32: A-frag of lane-group q4 = real keys 32g+8q4..+7
        __builtin_amdgcn_s_setprio(1);
#pragma unroll
        for (int g = 0; g < 2; ++g) {
            bf16x8 vB[4];
#pragma unroll
            for (int nt = 0; nt < 4; ++nt) {
                const int d = nt * 16 + c15;
                const int pc = (4 * g + q4) ^ (d & 7);
                vB[nt] = *(const bf16x8*)(sVT + d * 64 + pc * 8);
            }
            union { bf16x8 v; u32 u[4]; } ta;
            ta.u[0] = pu[2 * g][0];
            ta.u[1] = pu[2 * g][1];
            ta.u[2] = pu[2 * g + 1][0];
            ta.u[3] = pu[2 * g + 1][1];
#pragma unroll
            for (int nt = 0; nt < 4; ++nt)
                accO[nt] = __builtin_amdgcn_mfma_f32_16x16x32_bf16(
                    ta.v, vB[nt], accO[nt], 0, 0, 0);
        }
        __builtin_amdgcn_s_setprio(0);
    };

    // ---- prologue: tiles 0,1 in flight (8 loads/thread) ----
    stage(sK0, sV0, 0);
    stage(sK1, sV1, 1);

    // ---- main loop: T=0..28 (unroll 2), stage T+2 / T+3; peel 30,31 ----
    // vmcnt: 8 outstanding steady; VMCNT(4) -> tile T's 4 loads landed.
#pragma unroll 1
    for (int T = 0; T < 30; T += 2) {
        VMCNT(4);
        __builtin_amdgcn_s_barrier();
        __builtin_amdgcn_sched_barrier(0);
        compute64(sK0, sV0, T * 64);
        __builtin_amdgcn_s_barrier();
        __builtin_amdgcn_sched_barrier(0);
        stage(sK0, sV0, T + 2);

        VMCNT(4);
        __builtin_amdgcn_s_barrier();
        __builtin_amdgcn_sched_barrier(0);
        compute64(sK1, sV1, (T + 1) * 64);
        __builtin_amdgcn_s_barrier();
        __builtin_amdgcn_sched_barrier(0);
        stage(sK1, sV1, T + 3);
    }
    // T=30 (buf0): outstanding = {S30,S31} -> wait 4
    VMCNT(4);
    __builtin_amdgcn_s_barrier();
    __builtin_amdgcn_sched_barrier(0);
    compute64(sK0, sV0, 30 * 64);
    // T=31 (buf1): outstanding = {S31} -> wait 0
    VMCNT(0);
    __builtin_amdgcn_s_barrier();
    __builtin_amdgcn_sched_barrier(0);
    compute64(sK1, sV1, 31 * 64);

    // --- l reduction across q4 groups -> total per qrow=c15
    l_acc += __shfl_xor(l_acc, 16);
    l_acc += __shfl_xor(l_acc, 32);

    // --- epilogue: accO C-layout row=q4*4+rr, col=c15=d
    const int h = bh & 15;
    float inv[4];
#pragma unroll
    for (int rr = 0; rr < 4; ++rr)
        inv[rr] = 1.0f / __shfl(l_acc, q4 * 4 + rr);
#pragma unroll
    for (int nt = 0; nt < 4; ++nt)
#pragma unroll
        for (int rr = 0; rr < 4; ++rr) {
            const int qrow = qt * 64 + w * 16 + q4 * 4 + rr;
            const int d = nt * 16 + c15;
            out[(b * 2048 + qrow) * 1024 + h * 64 + d] = accO[nt][rr] * inv[rr];
        }
}

// ---------------------------------------------------------------------------
extern "C" void kernel_launch(void* const* d_in, const int* in_sizes, int n_in,
                              void* d_out, int out_size, void* d_ws, size_t ws_size,
                              hipStream_t stream)
{
    const float* hs   = (const float*)d_in[0];
    const float* mask = (const float*)d_in[1];
    const float* Wq   = (const float*)d_in[2];
    const float* bq   = (const float*)d_in[3];
    const float* Wk   = (const float*)d_in[4];
    const float* bk   = (const float*)d_in[5];
    const float* Wv   = (const float*)d_in[6];
    const float* bv   = (const float*)d_in[7];

    // workspace layout (u16 units)
    u16* ws   = (u16*)d_ws;
    u16* qw   = ws;                     // Q  [b,h,n,d] bf16
    u16* kw   = ws + 4194304;           // K  [b,h,n,d]
    u16* vtw  = ws + 8388608;           // V^T [b,h,d,n]
    u16* hsb  = ws + 12582912;          // hidden_states bf16 (cvt_all dst start)
    u16* wqb  = ws + 16777216;
    u16* wkb  = ws + 17825792;
    u16* wvb  = ws + 18874368;

    cvt_all<<<1024, 256, 0, stream>>>(hs, Wq, Wk, Wv, hsb);

    qkv_gemm<<<dim3(24, 32), 256, 0, stream>>>(hsb, wqb, wkb, wvb, bq, bk, bv, qw, kw, vtw);
    attn<<<dim3(32, 32), 256, 0, stream>>>(qw, kw, vtw, mask, (float*)d_out);
}